// Round 6
// baseline (186.792 us; speedup 1.0000x reference)
//
#include <hip/hip_runtime.h>

// GCN: out = A_hat( relu( A_hat(X) @ W1 + b1 ) @ (W2@Wl) ) + (b2@Wl + bl)
// where A_hat = D^-1/2 (A + I) D^-1/2, aggregations done at 16 features.
// Round 6: consolidation. 5 kernels: prep, fill(ELL), gather, mlp(LDS-reduced,
// no partials buffer), gather. Zero fp32 feature atomics, no prefix scan.

constexpr int IN_F  = 16;
constexpr int H1D   = 512;
constexpr int H2D   = 1024;
constexpr int OUTF  = 16;
constexpr int PAD   = 64;     // max in-degree supported (Poisson(8) graph: safe)
constexpr int MLP_C = 8;      // j-chunks (one per wave)
constexpr int MLP_J = H1D / MLP_C;   // 64 j per chunk

// K1 (block-partitioned, all parts independent):
//  b in [0,32)   : WfB[j*16+o] = sum_k W2[j][k]*Wl[k][o]   (direct, no atomics)
//  b in [32,64)  : W1T[j*16+k] = W1[k][j]
//  b == 64       : bf[o] = b2 @ Wl[:,o] + bl[o]            (16 threads)
//  b >= 65       : counts[i] = 0
__global__ void k_prep(int* __restrict__ counts, float* __restrict__ WfB,
                       float* __restrict__ bf, float* __restrict__ W1T,
                       const float* __restrict__ W1, const float* __restrict__ W2,
                       const float* __restrict__ Wl, const float* __restrict__ b2,
                       const float* __restrict__ bl, int n) {
  int b = blockIdx.x, tid = threadIdx.x;
  if (b < 32) {
    int g = b * 256 + tid;               // 0..8191
    int j = g >> 4, o = g & 15;
    const float* w2r = W2 + (size_t)j * H2D;
    float a0 = 0.f, a1 = 0.f, a2 = 0.f, a3 = 0.f;
#pragma unroll 4
    for (int k = 0; k < H2D; k += 4) {
      a0 = fmaf(w2r[k + 0], Wl[(k + 0) * OUTF + o], a0);
      a1 = fmaf(w2r[k + 1], Wl[(k + 1) * OUTF + o], a1);
      a2 = fmaf(w2r[k + 2], Wl[(k + 2) * OUTF + o], a2);
      a3 = fmaf(w2r[k + 3], Wl[(k + 3) * OUTF + o], a3);
    }
    WfB[j * OUTF + o] = (a0 + a1) + (a2 + a3);
  } else if (b < 64) {
    int t = (b - 32) * 256 + tid;        // 0..8191
    int j = t >> 4, k = t & 15;
    W1T[t] = W1[k * H1D + j];
  } else if (b == 64) {
    if (tid < OUTF) {
      float a0 = 0.f, a1 = 0.f, a2 = 0.f, a3 = 0.f;
      for (int k = 0; k < H2D; k += 4) {
        a0 = fmaf(b2[k + 0], Wl[(k + 0) * OUTF + tid], a0);
        a1 = fmaf(b2[k + 1], Wl[(k + 1) * OUTF + tid], a1);
        a2 = fmaf(b2[k + 2], Wl[(k + 2) * OUTF + tid], a2);
        a3 = fmaf(b2[k + 3], Wl[(k + 3) * OUTF + tid], a3);
      }
      bf[tid] = bl[tid] + (a0 + a1) + (a2 + a3);
    }
  } else {
    int i = (b - 65) * 256 + tid;
    if (i < n) counts[i] = 0;
  }
}

// K2: histogram + ELL fill in one pass (counts double as cursors)
__global__ void k_fill(const int* __restrict__ src, const int* __restrict__ dst,
                       int* __restrict__ counts, int* __restrict__ ell, int e) {
  int t = blockIdx.x * blockDim.x + threadIdx.x;
  if (t < e) {
    int d = dst[t];
    int slot = atomicAdd(&counts[d], 1);
    if (slot < PAD) ell[(size_t)d * PAD + slot] = src[t];
  }
}

// K3/K5: gather aggregation, 4 threads per node (one float4 chunk each).
// dinv computed inline from counts: dinv = rsqrt(1 + in-degree).
// O[i][q] = bias[q] + di * ( di * V[i][q] + sum_{s in N(i)} ds * V[s][q] )
__global__ __launch_bounds__(256) void k_gather(const float* __restrict__ V,
                                                const int* __restrict__ ell,
                                                const int* __restrict__ counts,
                                                const float* __restrict__ bias,
                                                float* __restrict__ O, int n) {
  int t = blockIdx.x * 256 + threadIdx.x;
  if (t >= n * 4) return;
  int i = t >> 2, q = t & 3;
  int cnt = counts[i];
  float di = rsqrtf(1.0f + (float)cnt);
  if (cnt > PAD) cnt = PAD;             // never triggers for this graph; safety
  float4 acc = ((const float4*)(V + (size_t)i * 16))[q];
  acc.x *= di; acc.y *= di; acc.z *= di; acc.w *= di;   // self-loop: di*V[i]
  const int* row = ell + (size_t)i * PAD;
  for (int k = 0; k < cnt; ++k) {
    int s = row[k];
    float ds = rsqrtf(1.0f + (float)counts[s]);
    float4 v = ((const float4*)(V + (size_t)s * 16))[q];
    acc.x = fmaf(v.x, ds, acc.x);
    acc.y = fmaf(v.y, ds, acc.y);
    acc.z = fmaf(v.z, ds, acc.z);
    acc.w = fmaf(v.w, ds, acc.w);
  }
  float4 o;
  if (bias) {
    float4 bq = ((const float4*)bias)[q];
    o = make_float4(fmaf(acc.x, di, bq.x), fmaf(acc.y, di, bq.y),
                    fmaf(acc.z, di, bq.z), fmaf(acc.w, di, bq.w));
  } else {
    o = make_float4(acc.x * di, acc.y * di, acc.z * di, acc.w * di);
  }
  ((float4*)O)[(size_t)i * 4 + q] = o;
}

// K4: G[i] = relu(Xa[i] @ W1 + b1) @ Wf.
// 512-thread block = 8 waves; wave w (wave-uniform tid>>6) handles j-chunk w
// (64 j's) for the block's 64 nodes (1 node per lane). Weight rows are
// wave-uniform -> s_load. Partials reduced via padded LDS (no global partials).
__global__ __launch_bounds__(512) void k_mlp(const float* __restrict__ Xa,
                                             const float* __restrict__ W1T,
                                             const float* __restrict__ b1,
                                             const float* __restrict__ WfB,
                                             float* __restrict__ G, int n) {
  __shared__ float sred[MLP_C * 64 * 17];      // pad 17: conflict-free
  int tid = threadIdx.x;
  int c  = tid >> 6;                           // wave id 0..7 (uniform per wave)
  int nl = tid & 63;                           // lane = node within block
  int i  = blockIdx.x * 64 + nl;
  int is = (i < n) ? i : 0;

  float x[16];
  const float4* xr = (const float4*)(Xa + (size_t)is * 16);
#pragma unroll
  for (int q = 0; q < 4; ++q) {
    float4 v = xr[q];
    x[q * 4 + 0] = v.x; x[q * 4 + 1] = v.y; x[q * 4 + 2] = v.z; x[q * 4 + 3] = v.w;
  }

  float a[16];
#pragma unroll
  for (int o = 0; o < 16; ++o) a[o] = 0.f;

  const float* w1p = W1T + c * MLP_J * 16;     // uniform -> SGPR base
  const float* wfp = WfB + c * MLP_J * 16;
  const float* b1p = b1 + c * MLP_J;

#pragma unroll 4
  for (int jj = 0; jj < MLP_J; ++jj) {
    const float* w1r = w1p + jj * 16;
    const float* wfr = wfp + jj * 16;
    float h0 = b1p[jj], h1 = 0.f, h2 = 0.f, h3 = 0.f;
#pragma unroll
    for (int k = 0; k < 4; ++k) {
      h0 = fmaf(x[k +  0], w1r[k +  0], h0);
      h1 = fmaf(x[k +  4], w1r[k +  4], h1);
      h2 = fmaf(x[k +  8], w1r[k +  8], h2);
      h3 = fmaf(x[k + 12], w1r[k + 12], h3);
    }
    float h = fmaxf((h0 + h1) + (h2 + h3), 0.f);
#pragma unroll
    for (int o = 0; o < 16; ++o) a[o] = fmaf(h, wfr[o], a[o]);
  }

  float* my = &sred[(c * 64 + nl) * 17];
#pragma unroll
  for (int o = 0; o < 16; ++o) my[o] = a[o];   // bank = (nl*17+o)%32: spread
  __syncthreads();

  // 1024 outputs (64 nodes x 16), 512 threads -> 2 each; coalesced G writes
#pragma unroll
  for (int r = tid; r < 64 * 16; r += 512) {
    int nl2 = r >> 4, o = r & 15;
    int ii = blockIdx.x * 64 + nl2;
    if (ii < n) {
      float s = 0.f;
#pragma unroll
      for (int cc = 0; cc < MLP_C; ++cc) s += sred[(cc * 64 + nl2) * 17 + o];
      G[(size_t)ii * 16 + o] = s;
    }
  }
}

extern "C" void kernel_launch(void* const* d_in, const int* in_sizes, int n_in,
                              void* d_out, int out_size, void* d_ws, size_t ws_size,
                              hipStream_t stream) {
  (void)n_in; (void)out_size; (void)ws_size;
  const float* X   = (const float*)d_in[0];
  const int*   gr  = (const int*)d_in[1];
  const float* W1  = (const float*)d_in[2];
  const float* b1  = (const float*)d_in[3];
  const float* W2  = (const float*)d_in[4];
  const float* b2  = (const float*)d_in[5];
  const float* Wl  = (const float*)d_in[6];
  const float* bl  = (const float*)d_in[7];

  int n = in_sizes[0] / IN_F;      // 20000
  int e = in_sizes[1] / 2;         // 160000
  const int* src = gr;
  const int* dst = gr + e;

  float* ws   = (float*)d_ws;
  float* Xa   = ws;                          // n*16
  float* G    = Xa + (size_t)n * 16;         // n*16
  float* WfB  = G + (size_t)n * 16;          // 16*512 (j-major [j][o])
  float* bf   = WfB + OUTF * H1D;            // 16
  float* W1T  = bf + 16;                     // 16*512 (j-major [j][k])
  int*   counts = (int*)(W1T + IN_F * H1D);  // n
  int*   ell    = counts + n;                // n*PAD
  float* out  = (float*)d_out;

  const int TPB = 256;
  int nb_n  = (n + TPB - 1) / TPB;           // 79
  int nb_e  = (e + TPB - 1) / TPB;
  int nb_n4 = (n * 4 + TPB - 1) / TPB;
  int nb_m  = (n + 63) / 64;                 // 313 mlp blocks

  // K1: weights fusion + transpose + zero counts (all-parallel)
  k_prep<<<65 + nb_n, TPB, 0, stream>>>(counts, WfB, bf, W1T, W1, W2, Wl, b2, bl, n);
  // K2: degree histogram + ELL fill
  k_fill<<<nb_e, TPB, 0, stream>>>(src, dst, counts, ell, e);
  // K3: Xa = A_hat X (gather, self-loop + dinv inline)
  k_gather<<<nb_n4, TPB, 0, stream>>>(X, ell, counts, nullptr, Xa, n);
  // K4: G = relu(Xa W1 + b1) Wf  (LDS-reduced, no partials)
  k_mlp<<<nb_m, 512, 0, stream>>>(Xa, W1T, b1, WfB, G, n);
  // K5: out = A_hat G + bf (gather, bias + self-loop + dinv inline)
  k_gather<<<nb_n4, TPB, 0, stream>>>(G, ell, counts, bf, out, n);
}

// Round 7
// 152.689 us; speedup vs baseline: 1.2233x; 1.2233x over previous
//
#include <hip/hip_runtime.h>

// GCN: out = A_hat( relu( A_hat(X) @ W1 + b1 ) @ (W2@Wl) ) + (b2@Wl + bl)
// where A_hat = D^-1/2 (A + I) D^-1/2, aggregations done at 16 features.
// Round 7: revert mlp to grid-chunked (blockIdx.y -> true SGPR weight base,
// s_load pipelining) + 2 nodes/thread for 2x arithmetic intensity per s_load.
// ELL gather path unchanged (proven). 6 kernels.

constexpr int IN_F  = 16;
constexpr int H1D   = 512;
constexpr int H2D   = 1024;
constexpr int OUTF  = 16;
constexpr int PAD   = 64;     // max in-degree supported (Poisson(8) graph: safe)
constexpr int MLP_C = 8;      // j-chunks (grid.y)
constexpr int MLP_J = H1D / MLP_C;   // 64 j per chunk

// K1 (block-partitioned, all parts independent):
//  b in [0,32)   : WfB[j*16+o] = sum_k W2[j][k]*Wl[k][o]   (direct, no atomics)
//  b in [32,64)  : W1T[j*16+k] = W1[k][j]
//  b == 64       : bf[o] = b2 @ Wl[:,o] + bl[o]            (16 threads)
//  b >= 65       : counts[i] = 0
__global__ void k_prep(int* __restrict__ counts, float* __restrict__ WfB,
                       float* __restrict__ bf, float* __restrict__ W1T,
                       const float* __restrict__ W1, const float* __restrict__ W2,
                       const float* __restrict__ Wl, const float* __restrict__ b2,
                       const float* __restrict__ bl, int n) {
  int b = blockIdx.x, tid = threadIdx.x;
  if (b < 32) {
    int g = b * 256 + tid;               // 0..8191
    int j = g >> 4, o = g & 15;
    const float* w2r = W2 + (size_t)j * H2D;
    float a0 = 0.f, a1 = 0.f, a2 = 0.f, a3 = 0.f;
#pragma unroll 4
    for (int k = 0; k < H2D; k += 4) {
      a0 = fmaf(w2r[k + 0], Wl[(k + 0) * OUTF + o], a0);
      a1 = fmaf(w2r[k + 1], Wl[(k + 1) * OUTF + o], a1);
      a2 = fmaf(w2r[k + 2], Wl[(k + 2) * OUTF + o], a2);
      a3 = fmaf(w2r[k + 3], Wl[(k + 3) * OUTF + o], a3);
    }
    WfB[j * OUTF + o] = (a0 + a1) + (a2 + a3);
  } else if (b < 64) {
    int t = (b - 32) * 256 + tid;        // 0..8191
    int j = t >> 4, k = t & 15;
    W1T[t] = W1[k * H1D + j];
  } else if (b == 64) {
    if (tid < OUTF) {
      float a0 = 0.f, a1 = 0.f, a2 = 0.f, a3 = 0.f;
      for (int k = 0; k < H2D; k += 4) {
        a0 = fmaf(b2[k + 0], Wl[(k + 0) * OUTF + tid], a0);
        a1 = fmaf(b2[k + 1], Wl[(k + 1) * OUTF + tid], a1);
        a2 = fmaf(b2[k + 2], Wl[(k + 2) * OUTF + tid], a2);
        a3 = fmaf(b2[k + 3], Wl[(k + 3) * OUTF + tid], a3);
      }
      bf[tid] = bl[tid] + (a0 + a1) + (a2 + a3);
    }
  } else {
    int i = (b - 65) * 256 + tid;
    if (i < n) counts[i] = 0;
  }
}

// K2: histogram + ELL fill in one pass (counts double as cursors)
__global__ void k_fill(const int* __restrict__ src, const int* __restrict__ dst,
                       int* __restrict__ counts, int* __restrict__ ell, int e) {
  int t = blockIdx.x * blockDim.x + threadIdx.x;
  if (t < e) {
    int d = dst[t];
    int slot = atomicAdd(&counts[d], 1);
    if (slot < PAD) ell[(size_t)d * PAD + slot] = src[t];
  }
}

// K3/K6: gather aggregation, 4 threads per node (one float4 chunk each).
// dinv computed inline from counts: dinv = rsqrt(1 + in-degree).
// O[i][q] = bias[q] + di * ( di * V[i][q] + sum_{s in N(i)} ds * V[s][q] )
__global__ __launch_bounds__(256) void k_gather(const float* __restrict__ V,
                                                const int* __restrict__ ell,
                                                const int* __restrict__ counts,
                                                const float* __restrict__ bias,
                                                float* __restrict__ O, int n) {
  int t = blockIdx.x * 256 + threadIdx.x;
  if (t >= n * 4) return;
  int i = t >> 2, q = t & 3;
  int cnt = counts[i];
  float di = rsqrtf(1.0f + (float)cnt);
  if (cnt > PAD) cnt = PAD;             // never triggers for this graph; safety
  float4 acc = ((const float4*)(V + (size_t)i * 16))[q];
  acc.x *= di; acc.y *= di; acc.z *= di; acc.w *= di;   // self-loop: di*V[i]
  const int* row = ell + (size_t)i * PAD;
  for (int k = 0; k < cnt; ++k) {
    int s = row[k];
    float ds = rsqrtf(1.0f + (float)counts[s]);
    float4 v = ((const float4*)(V + (size_t)s * 16))[q];
    acc.x = fmaf(v.x, ds, acc.x);
    acc.y = fmaf(v.y, ds, acc.y);
    acc.z = fmaf(v.z, ds, acc.z);
    acc.w = fmaf(v.w, ds, acc.w);
  }
  float4 o;
  if (bias) {
    float4 bq = ((const float4*)bias)[q];
    o = make_float4(fmaf(acc.x, di, bq.x), fmaf(acc.y, di, bq.y),
                    fmaf(acc.z, di, bq.z), fmaf(acc.w, di, bq.w));
  } else {
    o = make_float4(acc.x * di, acc.y * di, acc.z * di, acc.w * di);
  }
  ((float4*)O)[(size_t)i * 4 + q] = o;
}

// K4: partial MLP. Chunk c = blockIdx.y (true SGPR -> scalar weight loads).
// Each thread handles TWO nodes (i0 = b*512+t, i1 = i0+256): per weight row
// fetched, 64+2 VALU ops issue -> s_load latency fully hidden.
__global__ __launch_bounds__(256) void k_mlp_part(const float* __restrict__ Xa,
                                                  const float* __restrict__ W1T,
                                                  const float* __restrict__ b1,
                                                  const float* __restrict__ WfB,
                                                  float* __restrict__ part, int n) {
  int tid = threadIdx.x;
  int i0 = blockIdx.x * 512 + tid;
  int i1 = i0 + 256;
  int c  = blockIdx.y;
  bool v0 = (i0 < n), v1 = (i1 < n);
  int is0 = v0 ? i0 : 0, is1 = v1 ? i1 : 0;

  float x0[16], x1[16];
  const float4* xr0 = (const float4*)(Xa + (size_t)is0 * 16);
  const float4* xr1 = (const float4*)(Xa + (size_t)is1 * 16);
#pragma unroll
  for (int q = 0; q < 4; ++q) {
    float4 a = xr0[q], b = xr1[q];
    x0[q * 4 + 0] = a.x; x0[q * 4 + 1] = a.y; x0[q * 4 + 2] = a.z; x0[q * 4 + 3] = a.w;
    x1[q * 4 + 0] = b.x; x1[q * 4 + 1] = b.y; x1[q * 4 + 2] = b.z; x1[q * 4 + 3] = b.w;
  }

  float a0[16], a1[16];
#pragma unroll
  for (int o = 0; o < 16; ++o) { a0[o] = 0.f; a1[o] = 0.f; }

  const float* w1p = W1T + (size_t)c * MLP_J * 16;   // SGPR base
  const float* wfp = WfB + (size_t)c * MLP_J * 16;   // SGPR base
  const float* b1p = b1 + (size_t)c * MLP_J;

#pragma unroll 4
  for (int jj = 0; jj < MLP_J; ++jj) {
    const float* w1r = w1p + jj * 16;
    const float* wfr = wfp + jj * 16;
    float bj = b1p[jj];
    float p0 = bj, p1 = 0.f, p2 = 0.f, p3 = 0.f;
    float q0 = bj, q1 = 0.f, q2 = 0.f, q3 = 0.f;
#pragma unroll
    for (int k = 0; k < 4; ++k) {
      float wa = w1r[k], wb = w1r[k + 4], wc = w1r[k + 8], wd = w1r[k + 12];
      p0 = fmaf(x0[k +  0], wa, p0);
      p1 = fmaf(x0[k +  4], wb, p1);
      p2 = fmaf(x0[k +  8], wc, p2);
      p3 = fmaf(x0[k + 12], wd, p3);
      q0 = fmaf(x1[k +  0], wa, q0);
      q1 = fmaf(x1[k +  4], wb, q1);
      q2 = fmaf(x1[k +  8], wc, q2);
      q3 = fmaf(x1[k + 12], wd, q3);
    }
    float h0 = fmaxf((p0 + p1) + (p2 + p3), 0.f);
    float h1 = fmaxf((q0 + q1) + (q2 + q3), 0.f);
#pragma unroll
    for (int o = 0; o < 16; ++o) {
      float wv = wfr[o];
      a0[o] = fmaf(h0, wv, a0[o]);
      a1[o] = fmaf(h1, wv, a1[o]);
    }
  }

  float* pbase = part + (size_t)c * n * 16;
  if (v0) {
    float4* pr = (float4*)(pbase + (size_t)i0 * 16);
#pragma unroll
    for (int q = 0; q < 4; ++q)
      pr[q] = make_float4(a0[q * 4 + 0], a0[q * 4 + 1], a0[q * 4 + 2], a0[q * 4 + 3]);
  }
  if (v1) {
    float4* pr = (float4*)(pbase + (size_t)i1 * 16);
#pragma unroll
    for (int q = 0; q < 4; ++q)
      pr[q] = make_float4(a1[q * 4 + 0], a1[q * 4 + 1], a1[q * 4 + 2], a1[q * 4 + 3]);
  }
}

// K5: G[t4] = sum_c part[c][t4]
__global__ void k_comb(const float* __restrict__ part, float* __restrict__ G,
                       int n) {
  int t = blockIdx.x * blockDim.x + threadIdx.x;  // n*4 float4s
  if (t < n * 4) {
    const float4* p = (const float4*)part;
    size_t stride = (size_t)n * 4;
    float4 s = p[t];
#pragma unroll
    for (int c = 1; c < MLP_C; ++c) {
      float4 v = p[(size_t)c * stride + t];
      s.x += v.x; s.y += v.y; s.z += v.z; s.w += v.w;
    }
    ((float4*)G)[t] = s;
  }
}

extern "C" void kernel_launch(void* const* d_in, const int* in_sizes, int n_in,
                              void* d_out, int out_size, void* d_ws, size_t ws_size,
                              hipStream_t stream) {
  (void)n_in; (void)out_size; (void)ws_size;
  const float* X   = (const float*)d_in[0];
  const int*   gr  = (const int*)d_in[1];
  const float* W1  = (const float*)d_in[2];
  const float* b1  = (const float*)d_in[3];
  const float* W2  = (const float*)d_in[4];
  const float* b2  = (const float*)d_in[5];
  const float* Wl  = (const float*)d_in[6];
  const float* bl  = (const float*)d_in[7];

  int n = in_sizes[0] / IN_F;      // 20000
  int e = in_sizes[1] / 2;         // 160000
  const int* src = gr;
  const int* dst = gr + e;

  float* ws   = (float*)d_ws;
  float* Xa   = ws;                          // n*16
  float* G    = Xa + (size_t)n * 16;         // n*16
  float* WfB  = G + (size_t)n * 16;          // 16*512 (j-major [j][o])
  float* bf   = WfB + OUTF * H1D;            // 16
  float* W1T  = bf + 16;                     // 16*512 (j-major [j][k])
  int*   counts = (int*)(W1T + IN_F * H1D);  // n
  int*   ell    = counts + n;                // n*PAD
  float* part   = (float*)(ell + (size_t)n * PAD);  // MLP_C*n*16
  float* out  = (float*)d_out;

  const int TPB = 256;
  int nb_n  = (n + TPB - 1) / TPB;           // 79
  int nb_e  = (e + TPB - 1) / TPB;
  int nb_n4 = (n * 4 + TPB - 1) / TPB;
  int nb_m  = (n + 511) / 512;               // 40 (x-dim of mlp grid)

  // K1: weights fusion + transpose + zero counts (all-parallel)
  k_prep<<<65 + nb_n, TPB, 0, stream>>>(counts, WfB, bf, W1T, W1, W2, Wl, b2, bl, n);
  // K2: degree histogram + ELL fill
  k_fill<<<nb_e, TPB, 0, stream>>>(src, dst, counts, ell, e);
  // K3: Xa = A_hat X (gather, self-loop + dinv inline)
  k_gather<<<nb_n4, TPB, 0, stream>>>(X, ell, counts, nullptr, Xa, n);
  // K4+K5: G = relu(Xa W1 + b1) Wf
  dim3 mg(nb_m, MLP_C);
  k_mlp_part<<<mg, TPB, 0, stream>>>(Xa, W1T, b1, WfB, part, n);
  k_comb<<<nb_n4, TPB, 0, stream>>>(part, G, n);
  // K6: out = A_hat G + bf (gather, bias + self-loop + dinv inline)
  k_gather<<<nb_n4, TPB, 0, stream>>>(G, ell, counts, bf, out, n);
}

// Round 8
// 150.066 us; speedup vs baseline: 1.2447x; 1.0175x over previous
//
#include <hip/hip_runtime.h>

// GCN: out = A_hat( relu( A_hat(X) @ W1 + b1 ) @ (W2@Wl) ) + (b2@Wl + bl)
// where A_hat = D^-1/2 (A + I) D^-1/2, aggregations done at 16 features.
// Round 8: mlp weights staged in LDS (broadcast ds_read, no s_load latency
// chain), 1 node/thread, C=8 chunks (2.47 waves/SIMD). ELL gather unchanged.

constexpr int IN_F  = 16;
constexpr int H1D   = 512;
constexpr int H2D   = 1024;
constexpr int OUTF  = 16;
constexpr int PAD   = 64;     // max in-degree supported (Poisson(8) graph: safe)
constexpr int MLP_C = 8;      // j-chunks (grid.y)
constexpr int MLP_J = H1D / MLP_C;   // 64 j per chunk

// K1 (block-partitioned, all parts independent):
//  b in [0,32)   : WfB[j*16+o] = sum_k W2[j][k]*Wl[k][o]   (direct, no atomics)
//  b in [32,64)  : W1T[j*16+k] = W1[k][j]
//  b == 64       : bf[o] = b2 @ Wl[:,o] + bl[o]            (16 threads)
//  b >= 65       : counts[i] = 0
__global__ void k_prep(int* __restrict__ counts, float* __restrict__ WfB,
                       float* __restrict__ bf, float* __restrict__ W1T,
                       const float* __restrict__ W1, const float* __restrict__ W2,
                       const float* __restrict__ Wl, const float* __restrict__ b2,
                       const float* __restrict__ bl, int n) {
  int b = blockIdx.x, tid = threadIdx.x;
  if (b < 32) {
    int g = b * 256 + tid;               // 0..8191
    int j = g >> 4, o = g & 15;
    const float* w2r = W2 + (size_t)j * H2D;
    float a0 = 0.f, a1 = 0.f, a2 = 0.f, a3 = 0.f;
#pragma unroll 4
    for (int k = 0; k < H2D; k += 4) {
      a0 = fmaf(w2r[k + 0], Wl[(k + 0) * OUTF + o], a0);
      a1 = fmaf(w2r[k + 1], Wl[(k + 1) * OUTF + o], a1);
      a2 = fmaf(w2r[k + 2], Wl[(k + 2) * OUTF + o], a2);
      a3 = fmaf(w2r[k + 3], Wl[(k + 3) * OUTF + o], a3);
    }
    WfB[j * OUTF + o] = (a0 + a1) + (a2 + a3);
  } else if (b < 64) {
    int t = (b - 32) * 256 + tid;        // 0..8191
    int j = t >> 4, k = t & 15;
    W1T[t] = W1[k * H1D + j];
  } else if (b == 64) {
    if (tid < OUTF) {
      float a0 = 0.f, a1 = 0.f, a2 = 0.f, a3 = 0.f;
      for (int k = 0; k < H2D; k += 4) {
        a0 = fmaf(b2[k + 0], Wl[(k + 0) * OUTF + tid], a0);
        a1 = fmaf(b2[k + 1], Wl[(k + 1) * OUTF + tid], a1);
        a2 = fmaf(b2[k + 2], Wl[(k + 2) * OUTF + tid], a2);
        a3 = fmaf(b2[k + 3], Wl[(k + 3) * OUTF + tid], a3);
      }
      bf[tid] = bl[tid] + (a0 + a1) + (a2 + a3);
    }
  } else {
    int i = (b - 65) * 256 + tid;
    if (i < n) counts[i] = 0;
  }
}

// K2: histogram + ELL fill in one pass (counts double as cursors)
__global__ void k_fill(const int* __restrict__ src, const int* __restrict__ dst,
                       int* __restrict__ counts, int* __restrict__ ell, int e) {
  int t = blockIdx.x * blockDim.x + threadIdx.x;
  if (t < e) {
    int d = dst[t];
    int slot = atomicAdd(&counts[d], 1);
    if (slot < PAD) ell[(size_t)d * PAD + slot] = src[t];
  }
}

// K3/K6: gather aggregation, 4 threads per node (one float4 chunk each).
// dinv computed inline from counts: dinv = rsqrt(1 + in-degree).
// O[i][q] = bias[q] + di * ( di * V[i][q] + sum_{s in N(i)} ds * V[s][q] )
__global__ __launch_bounds__(256) void k_gather(const float* __restrict__ V,
                                                const int* __restrict__ ell,
                                                const int* __restrict__ counts,
                                                const float* __restrict__ bias,
                                                float* __restrict__ O, int n) {
  int t = blockIdx.x * 256 + threadIdx.x;
  if (t >= n * 4) return;
  int i = t >> 2, q = t & 3;
  int cnt = counts[i];
  float di = rsqrtf(1.0f + (float)cnt);
  if (cnt > PAD) cnt = PAD;             // never triggers for this graph; safety
  float4 acc = ((const float4*)(V + (size_t)i * 16))[q];
  acc.x *= di; acc.y *= di; acc.z *= di; acc.w *= di;   // self-loop: di*V[i]
  const int* row = ell + (size_t)i * PAD;
  for (int k = 0; k < cnt; ++k) {
    int s = row[k];
    float ds = rsqrtf(1.0f + (float)counts[s]);
    float4 v = ((const float4*)(V + (size_t)s * 16))[q];
    acc.x = fmaf(v.x, ds, acc.x);
    acc.y = fmaf(v.y, ds, acc.y);
    acc.z = fmaf(v.z, ds, acc.z);
    acc.w = fmaf(v.w, ds, acc.w);
  }
  float4 o;
  if (bias) {
    float4 bq = ((const float4*)bias)[q];
    o = make_float4(fmaf(acc.x, di, bq.x), fmaf(acc.y, di, bq.y),
                    fmaf(acc.z, di, bq.z), fmaf(acc.w, di, bq.w));
  } else {
    o = make_float4(acc.x * di, acc.y * di, acc.z * di, acc.w * di);
  }
  ((float4*)O)[(size_t)i * 4 + q] = o;
}

// K4: partial MLP. Chunk c = blockIdx.y. Chunk weights staged in LDS once per
// block (8.25 KB); inner loop reads them with uniform-address float4 LDS reads
// (hardware broadcast, conflict-free). One node per thread, x and a in regs.
__global__ __launch_bounds__(256) void k_mlp_part(const float* __restrict__ Xa,
                                                  const float* __restrict__ W1T,
                                                  const float* __restrict__ b1,
                                                  const float* __restrict__ WfB,
                                                  float* __restrict__ part, int n) {
  __shared__ float w1s[MLP_J * 16];    // 4 KB
  __shared__ float wfs[MLP_J * 16];    // 4 KB
  __shared__ float b1s[MLP_J];         // 256 B
  int tid = threadIdx.x;
  int c  = blockIdx.y;

  {  // stage chunk weights: coalesced float4 loads, one iter each
    const float4* s1 = (const float4*)(W1T + (size_t)c * MLP_J * 16);
    const float4* s2 = (const float4*)(WfB + (size_t)c * MLP_J * 16);
    ((float4*)w1s)[tid] = s1[tid];     // 256 float4 = 4 KB
    ((float4*)wfs)[tid] = s2[tid];
    if (tid < MLP_J) b1s[tid] = b1[(size_t)c * MLP_J + tid];
  }
  __syncthreads();

  int i = blockIdx.x * 256 + tid;
  bool valid = (i < n);
  int is = valid ? i : 0;

  float x[16];
  const float4* xr = (const float4*)(Xa + (size_t)is * 16);
#pragma unroll
  for (int q = 0; q < 4; ++q) {
    float4 v = xr[q];
    x[q * 4 + 0] = v.x; x[q * 4 + 1] = v.y; x[q * 4 + 2] = v.z; x[q * 4 + 3] = v.w;
  }

  float a[16];
#pragma unroll
  for (int o = 0; o < 16; ++o) a[o] = 0.f;

#pragma unroll 4
  for (int jj = 0; jj < MLP_J; ++jj) {
    const float4* w1v = (const float4*)(w1s + jj * 16);  // uniform addr: bcast
    const float4* wfv = (const float4*)(wfs + jj * 16);
    float4 wA = w1v[0], wB = w1v[1], wC = w1v[2], wD = w1v[3];
    float h0 = b1s[jj], h1 = 0.f, h2 = 0.f, h3 = 0.f;
    h0 = fmaf(x[ 0], wA.x, h0); h0 = fmaf(x[ 1], wA.y, h0);
    h0 = fmaf(x[ 2], wA.z, h0); h0 = fmaf(x[ 3], wA.w, h0);
    h1 = fmaf(x[ 4], wB.x, h1); h1 = fmaf(x[ 5], wB.y, h1);
    h1 = fmaf(x[ 6], wB.z, h1); h1 = fmaf(x[ 7], wB.w, h1);
    h2 = fmaf(x[ 8], wC.x, h2); h2 = fmaf(x[ 9], wC.y, h2);
    h2 = fmaf(x[10], wC.z, h2); h2 = fmaf(x[11], wC.w, h2);
    h3 = fmaf(x[12], wD.x, h3); h3 = fmaf(x[13], wD.y, h3);
    h3 = fmaf(x[14], wD.z, h3); h3 = fmaf(x[15], wD.w, h3);
    float h = fmaxf((h0 + h1) + (h2 + h3), 0.f);
    float4 fA = wfv[0], fB = wfv[1], fC = wfv[2], fD = wfv[3];
    a[ 0] = fmaf(h, fA.x, a[ 0]); a[ 1] = fmaf(h, fA.y, a[ 1]);
    a[ 2] = fmaf(h, fA.z, a[ 2]); a[ 3] = fmaf(h, fA.w, a[ 3]);
    a[ 4] = fmaf(h, fB.x, a[ 4]); a[ 5] = fmaf(h, fB.y, a[ 5]);
    a[ 6] = fmaf(h, fB.z, a[ 6]); a[ 7] = fmaf(h, fB.w, a[ 7]);
    a[ 8] = fmaf(h, fC.x, a[ 8]); a[ 9] = fmaf(h, fC.y, a[ 9]);
    a[10] = fmaf(h, fC.z, a[10]); a[11] = fmaf(h, fC.w, a[11]);
    a[12] = fmaf(h, fD.x, a[12]); a[13] = fmaf(h, fD.y, a[13]);
    a[14] = fmaf(h, fD.z, a[14]); a[15] = fmaf(h, fD.w, a[15]);
  }

  if (valid) {
    float4* pr = (float4*)(part + ((size_t)c * n + i) * 16);
#pragma unroll
    for (int q = 0; q < 4; ++q)
      pr[q] = make_float4(a[q * 4 + 0], a[q * 4 + 1], a[q * 4 + 2], a[q * 4 + 3]);
  }
}

// K5: G[t4] = sum_c part[c][t4]
__global__ void k_comb(const float* __restrict__ part, float* __restrict__ G,
                       int n) {
  int t = blockIdx.x * blockDim.x + threadIdx.x;  // n*4 float4s
  if (t < n * 4) {
    const float4* p = (const float4*)part;
    size_t stride = (size_t)n * 4;
    float4 s = p[t];
#pragma unroll
    for (int c = 1; c < MLP_C; ++c) {
      float4 v = p[(size_t)c * stride + t];
      s.x += v.x; s.y += v.y; s.z += v.z; s.w += v.w;
    }
    ((float4*)G)[t] = s;
  }
}

extern "C" void kernel_launch(void* const* d_in, const int* in_sizes, int n_in,
                              void* d_out, int out_size, void* d_ws, size_t ws_size,
                              hipStream_t stream) {
  (void)n_in; (void)out_size; (void)ws_size;
  const float* X   = (const float*)d_in[0];
  const int*   gr  = (const int*)d_in[1];
  const float* W1  = (const float*)d_in[2];
  const float* b1  = (const float*)d_in[3];
  const float* W2  = (const float*)d_in[4];
  const float* b2  = (const float*)d_in[5];
  const float* Wl  = (const float*)d_in[6];
  const float* bl  = (const float*)d_in[7];

  int n = in_sizes[0] / IN_F;      // 20000
  int e = in_sizes[1] / 2;         // 160000
  const int* src = gr;
  const int* dst = gr + e;

  float* ws   = (float*)d_ws;
  float* Xa   = ws;                          // n*16
  float* G    = Xa + (size_t)n * 16;         // n*16
  float* WfB  = G + (size_t)n * 16;          // 16*512 (j-major [j][o])
  float* bf   = WfB + OUTF * H1D;            // 16
  float* W1T  = bf + 16;                     // 16*512 (j-major [j][k])
  int*   counts = (int*)(W1T + IN_F * H1D);  // n
  int*   ell    = counts + n;                // n*PAD
  float* part   = (float*)(ell + (size_t)n * PAD);  // MLP_C*n*16
  float* out  = (float*)d_out;

  const int TPB = 256;
  int nb_n  = (n + TPB - 1) / TPB;           // 79
  int nb_e  = (e + TPB - 1) / TPB;
  int nb_n4 = (n * 4 + TPB - 1) / TPB;

  // K1: weights fusion + transpose + zero counts (all-parallel)
  k_prep<<<65 + nb_n, TPB, 0, stream>>>(counts, WfB, bf, W1T, W1, W2, Wl, b2, bl, n);
  // K2: degree histogram + ELL fill
  k_fill<<<nb_e, TPB, 0, stream>>>(src, dst, counts, ell, e);
  // K3: Xa = A_hat X (gather, self-loop + dinv inline)
  k_gather<<<nb_n4, TPB, 0, stream>>>(X, ell, counts, nullptr, Xa, n);
  // K4+K5: G = relu(Xa W1 + b1) Wf
  dim3 mg(nb_n, MLP_C);
  k_mlp_part<<<mg, TPB, 0, stream>>>(Xa, W1T, b1, WfB, part, n);
  k_comb<<<nb_n4, TPB, 0, stream>>>(part, G, n);
  // K6: out = A_hat G + bf (gather, bias + self-loop + dinv inline)
  k_gather<<<nb_n4, TPB, 0, stream>>>(G, ell, counts, bf, out, n);
}